// Round 3
// baseline (919.948 us; speedup 1.0000x reference)
//
#include <hip/hip_runtime.h>
#include <stdint.h>
#include <math.h>

#define HW    524288      // 512*1024 pixels
#define NETA  7
#define F     68          // NPROG*LEV

// ---------------- threefry2x32, key = (0, 42)  [jax.random.key(42)] ----------------
// jax_threefry_partitionable=True (default, JAX >= 0.5): for element index i,
// counter = (hi32(i), lo32(i)) = (0, i), and the 32-bit random word is the
// XOR of the two threefry output words: bits = o0 ^ o1.
__device__ __forceinline__ uint32_t threefry_xor_k42(uint32_t x0, uint32_t x1) {
  const uint32_t ks0 = 0u;
  const uint32_t ks1 = 42u;
  const uint32_t ks2 = 0x1BD11BDAu ^ ks0 ^ ks1;
  x0 += ks0; x1 += ks1;
#define RND(r) { x0 += x1; x1 = (x1 << (r)) | (x1 >> (32 - (r))); x1 ^= x0; }
  RND(13) RND(15) RND(26) RND(6)   x0 += ks1; x1 += ks2 + 1u;
  RND(17) RND(29) RND(16) RND(24)  x0 += ks2; x1 += ks0 + 2u;
  RND(13) RND(15) RND(26) RND(6)   x0 += ks0; x1 += ks1 + 3u;
  RND(17) RND(29) RND(16) RND(24)  x0 += ks1; x1 += ks2 + 4u;
  RND(13) RND(15) RND(26) RND(6)   x0 += ks2; x1 += ks0 + 5u;
#undef RND
  return x0 ^ x1;
}

// jax uniform(minval=tiny,maxval=1) bits->float (bit-exact), then gumbel in
// double (tracks the true value; argmax decisions robust to f32-vs-f64 ties
// at ~1e-7 probability scale).
__device__ __forceinline__ double gumbel_from_bits(uint32_t bits) {
  float f = __uint_as_float((bits >> 9) | 0x3f800000u) - 1.0f;  // [0, 1-2^-23], exact
  double u = (f == 0.0f) ? (double)1.1754943508222875e-38f : (double)f;
  return -log(-log(u));
}

// ---------------- kernel 1: categorical sampling of new_eta ----------------
// One thread per pixel p; element index for class k is i = 7*p + k
// (gumbel tensor shape (H, W, 7), row-major iota).
__global__ void __launch_bounds__(256) eta_kernel(const float* __restrict__ T,
                                                  const int* __restrict__ eta,
                                                  int* __restrict__ eta_new) {
  __shared__ double lgt[NETA * NETA];
  const int tid = threadIdx.x;
  if (tid < NETA * NETA) lgt[tid] = log((double)T[tid] + 1e-9);
  __syncthreads();

  const int p = blockIdx.x * 256 + tid;
  const int r = eta[p];

  double best = -1e300;
  int e = 0;
#pragma unroll
  for (int k = 0; k < NETA; k++) {
    const uint32_t i = (uint32_t)(7 * p + k);        // < 2^32, hi word = 0
    const uint32_t bits = threefry_xor_k42(0u, i);
    const double v = gumbel_from_bits(bits) + lgt[r * NETA + k];
    if (v > best) { best = v; e = k; }               // strict > == first-max (jnp.argmax)
  }
  eta_new[p] = e;
}

// ---------------- kernel 2: selected-expert matvec per pixel ----------------
// thread p: out[:, p] = W[e(p)] @ x[:, p] + b[e(p)], f32.
// x/out accesses fully coalesced (lane = pixel). W float4 loads: <=7 distinct
// 16B segments per wave instruction, L2-resident (129.5 KB working set).
__global__ void __launch_bounds__(256) expert_kernel(const float* __restrict__ x,
                                                     const float* __restrict__ W,
                                                     const float* __restrict__ b,
                                                     const int* __restrict__ eta_new,
                                                     float* __restrict__ out) {
  const int p = blockIdx.x * 256 + threadIdx.x;
  const int e = eta_new[p];
  const float* __restrict__ Wp = W + (size_t)e * (F * F);

  float acc[F];
#pragma unroll
  for (int o = 0; o < F; o++) acc[o] = 0.0f;

#pragma unroll 1
  for (int fc = 0; fc < F / 4; fc++) {
    const float xv0 = x[(size_t)(4 * fc + 0) * HW + p];
    const float xv1 = x[(size_t)(4 * fc + 1) * HW + p];
    const float xv2 = x[(size_t)(4 * fc + 2) * HW + p];
    const float xv3 = x[(size_t)(4 * fc + 3) * HW + p];
#pragma unroll
    for (int o = 0; o < F; o++) {
      const float4 w = *reinterpret_cast<const float4*>(Wp + o * F + 4 * fc);
      float a = acc[o];
      a = fmaf(w.x, xv0, a);
      a = fmaf(w.y, xv1, a);
      a = fmaf(w.z, xv2, a);
      a = fmaf(w.w, xv3, a);
      acc[o] = a;
    }
  }

  const float* __restrict__ bp = b + e * F;
#pragma unroll
  for (int o = 0; o < F; o++) out[(size_t)o * HW + p] = acc[o] + bp[o];
}

extern "C" void kernel_launch(void* const* d_in, const int* in_sizes, int n_in,
                              void* d_out, int out_size, void* d_ws, size_t ws_size,
                              hipStream_t stream) {
  const float* x   = (const float*)d_in[0];
  const float* W   = (const float*)d_in[1];
  const float* b   = (const float*)d_in[2];
  const float* T   = (const float*)d_in[3];
  const int*   eta = (const int*)d_in[4];
  float* out = (float*)d_out;

  // eta scratch: prefer d_ws; fall back to the last output row (each thread of
  // expert_kernel reads its own etabuf[p] before overwriting out[67*HW+p]).
  int* etabuf = (ws_size >= sizeof(int) * (size_t)HW)
                    ? (int*)d_ws
                    : ((int*)d_out) + (size_t)(F - 1) * HW;

  eta_kernel<<<HW / 256, 256, 0, stream>>>(T, eta, etabuf);
  expert_kernel<<<HW / 256, 256, 0, stream>>>(x, W, b, etabuf, out);
}

// Round 4
// 791.878 us; speedup vs baseline: 1.1617x; 1.1617x over previous
//
#include <hip/hip_runtime.h>
#include <stdint.h>
#include <math.h>

#define HW    524288      // 512*1024 pixels
#define NETA  7
#define F     68          // NPROG*LEV
#define OC    17          // outputs per thread (F/4)

// ---------------- threefry2x32, key = (0, 42)  [jax.random.key(42)] ----------------
// jax_threefry_partitionable=True (default): counter=(0,i), bits = o0 ^ o1.
// Verified bit-exact vs np reference in round 3 (absmax 0.0).
__device__ __forceinline__ uint32_t threefry_xor_k42(uint32_t x0, uint32_t x1) {
  const uint32_t ks0 = 0u;
  const uint32_t ks1 = 42u;
  const uint32_t ks2 = 0x1BD11BDAu ^ ks0 ^ ks1;
  x0 += ks0; x1 += ks1;
#define RND(r) { x0 += x1; x1 = (x1 << (r)) | (x1 >> (32 - (r))); x1 ^= x0; }
  RND(13) RND(15) RND(26) RND(6)   x0 += ks1; x1 += ks2 + 1u;
  RND(17) RND(29) RND(16) RND(24)  x0 += ks2; x1 += ks0 + 2u;
  RND(13) RND(15) RND(26) RND(6)   x0 += ks0; x1 += ks1 + 3u;
  RND(17) RND(29) RND(16) RND(24)  x0 += ks1; x1 += ks2 + 4u;
  RND(13) RND(15) RND(26) RND(6)   x0 += ks2; x1 += ks0 + 5u;
#undef RND
  return x0 ^ x1;
}

// ---------------- kernel 1: categorical sampling via exponential race ----------------
// argmax_k [gumbel_k + log(T[r,k]+1e-9)]  ==  argmin_k [(-ln u_k) / (T[r,k]+1e-9)]
// (strictly monotone transform; tie order preserved by strict <).
// f32 screen with hw v_log_f32 (log2 — uniform scale, order-invariant); f64
// fallback when top-2 relative gap < 3e-5 (err bound ~3e-7, 100x margin;
// expected fallback ~2e1 pixels of 524288).
__global__ void __launch_bounds__(256) eta_kernel(const float* __restrict__ T,
                                                  const int* __restrict__ eta,
                                                  int* __restrict__ eta_new) {
  __shared__ float  rinv32[NETA * NETA];
  __shared__ double rinv64[NETA * NETA];
  const int tid = threadIdx.x;
  if (tid < NETA * NETA) {
    double d = 1.0 / ((double)T[tid] + 1e-9);
    rinv64[tid] = d;
    rinv32[tid] = (float)d;
  }
  __syncthreads();

  const int p = blockIdx.x * 256 + tid;
  const int r = eta[p];

  float w[NETA];
#pragma unroll
  for (int k = 0; k < NETA; k++) {
    const uint32_t bits = threefry_xor_k42(0u, (uint32_t)(7 * p + k));
    const float f = __uint_as_float((bits >> 9) | 0x3f800000u) - 1.0f;
    const float u = (f == 0.0f) ? 1.1754943508222875e-38f : f;
    w[k] = (-__log2f(u)) * rinv32[r * NETA + k];
  }
  float w1 = w[0], w2 = 3.4e38f;
  int e = 0;
#pragma unroll
  for (int k = 1; k < NETA; k++) {
    if (w[k] < w1)      { w2 = w1; w1 = w[k]; e = k; }
    else if (w[k] < w2) { w2 = w[k]; }
  }
  if (!((w2 - w1) > 3e-5f * w2)) {           // ambiguous -> exact f64 race (rare)
    double b1 = 1e300;
    e = 0;
    for (int k = 0; k < NETA; k++) {
      const uint32_t bits = threefry_xor_k42(0u, (uint32_t)(7 * p + k));
      const float f = __uint_as_float((bits >> 9) | 0x3f800000u) - 1.0f;
      const double u = (f == 0.0f) ? (double)1.1754943508222875e-38f : (double)f;
      const double wv = -log(u) * rinv64[r * NETA + k];
      if (wv < b1) { b1 = wv; e = k; }
    }
  }
  eta_new[p] = e;
}

// ---------------- kernel 2: selected-expert matvec, 4 threads per pixel ----------------
// Block = 64 pixels x 4 o-chunks. x staged in LDS once (conflict-free both ways).
// Each thread: acc[17] (fits registers under the 128-VGPR cap of bounds(256,4)).
__global__ void __launch_bounds__(256, 4) expert_kernel(const float* __restrict__ x,
                                                        const float* __restrict__ W,
                                                        const float* __restrict__ b,
                                                        const int* __restrict__ eta_new,
                                                        float* __restrict__ out) {
  __shared__ float xs[F][64];                 // 17408 B
  const int tid = threadIdx.x;
  const int pl  = tid & 63;                   // pixel lane within block
  const int c   = tid >> 6;                   // o-chunk 0..3
  const int p   = blockIdx.x * 64 + pl;

  const int e = eta_new[p];

  // stage x: thread (c,pl) loads rows f = c + 4*i  (coalesced 256B per row)
#pragma unroll
  for (int i = 0; i < 17; i++) {
    const int f = c + 4 * i;
    xs[f][pl] = x[(size_t)f * HW + p];
  }
  __syncthreads();

  const float* __restrict__ Wp = W + (size_t)e * (F * F) + (size_t)(c * OC) * F;

  float acc[OC];
#pragma unroll
  for (int o = 0; o < OC; o++) acc[o] = 0.0f;

#pragma unroll 1
  for (int f4 = 0; f4 < F / 4; f4++) {
    const float xv0 = xs[4 * f4 + 0][pl];
    const float xv1 = xs[4 * f4 + 1][pl];
    const float xv2 = xs[4 * f4 + 2][pl];
    const float xv3 = xs[4 * f4 + 3][pl];
#pragma unroll
    for (int o = 0; o < OC; o++) {
      const float4 w = *reinterpret_cast<const float4*>(Wp + o * F + 4 * f4);
      float a = acc[o];
      a = fmaf(w.x, xv0, a);
      a = fmaf(w.y, xv1, a);
      a = fmaf(w.z, xv2, a);
      a = fmaf(w.w, xv3, a);
      acc[o] = a;
    }
  }

  const float* __restrict__ bp = b + e * F + c * OC;
#pragma unroll
  for (int o = 0; o < OC; o++)
    out[(size_t)(c * OC + o) * HW + p] = acc[o] + bp[o];
}

extern "C" void kernel_launch(void* const* d_in, const int* in_sizes, int n_in,
                              void* d_out, int out_size, void* d_ws, size_t ws_size,
                              hipStream_t stream) {
  const float* x   = (const float*)d_in[0];
  const float* W   = (const float*)d_in[1];
  const float* b   = (const float*)d_in[2];
  const float* T   = (const float*)d_in[3];
  const int*   eta = (const int*)d_in[4];
  float* out = (float*)d_out;

  int* etabuf = (ws_size >= sizeof(int) * (size_t)HW)
                    ? (int*)d_ws
                    : ((int*)d_out) + (size_t)(F - 1) * HW;

  eta_kernel<<<HW / 256, 256, 0, stream>>>(T, eta, etabuf);
  expert_kernel<<<HW / 64, 256, 0, stream>>>(x, W, b, etabuf, out);
}